// Round 4
// baseline (708.861 us; speedup 1.0000x reference)
//
#include <hip/hip_runtime.h>

#define BB 16
#define NN 2048
#define DD 128
#define KS 4
#define KC (NN / KS)

typedef __attribute__((ext_vector_type(8))) __bf16 bf16x8;
typedef __attribute__((ext_vector_type(4))) float f32x4;
typedef __attribute__((ext_vector_type(4))) unsigned int u32x4;
typedef __attribute__((address_space(3))) unsigned int lds_u32;
typedef __attribute__((address_space(1))) const unsigned int glob_u32;

static __device__ __forceinline__ unsigned short f2b(float f) {
  union { float f; unsigned int u; } c; c.f = f;
  unsigned int u = c.u;
  unsigned int r = (u + 0x7FFFu + ((u >> 16) & 1u)) >> 16;
  return (unsigned short)r;
}
static __device__ __forceinline__ float b2f(unsigned short u) {
  union { unsigned int u; float f; } c; c.u = ((unsigned int)u) << 16;
  return c.f;
}

// WT[l][e][d] = bf16(W[l][d][e])  -- 96 KB total, L2-resident afterwards
__global__ void k_wt(const float* __restrict__ W, unsigned short* __restrict__ WT) {
  __shared__ float t[64][65];
  int l = blockIdx.z, d0 = blockIdx.x * 64, e0 = blockIdx.y * 64;
  int tid = threadIdx.x;
  const float* src = W + (size_t)l * DD * DD;
  for (int p = 0; p < 16; ++p) {
    int idx = p * 256 + tid;
    int d = idx >> 6, e = idx & 63;
    t[e][d] = src[(size_t)(d0 + d) * DD + (e0 + e)];
  }
  __syncthreads();
  unsigned short* dst = WT + (size_t)l * DD * DD;
  for (int p = 0; p < 4; ++p) {
    int idx = p * 256 + tid;
    int e = idx >> 4, d4 = (idx & 15) * 4;
    ushort4 r;
    r.x = f2b(t[e][d4 + 0]); r.y = f2b(t[e][d4 + 1]);
    r.z = f2b(t[e][d4 + 2]); r.w = f2b(t[e][d4 + 3]);
    *(ushort4*)(dst + (size_t)(e0 + e) * DD + (d0 + d4)) = r;
  }
}

// Merged: x<1024 -> adj transpose tile; x>=1024 -> layer-0 gemm1 (X fp32, WT global frags)
__global__ __launch_bounds__(256) void k_pre(const float* __restrict__ adj,
                                             unsigned short* __restrict__ adjT,
                                             const float* __restrict__ X,
                                             const unsigned short* __restrict__ WT,
                                             unsigned short* __restrict__ hwT) {
  int b = blockIdx.y, x = blockIdx.x, tid = threadIdx.x;
  if (x < 1024) {
    __shared__ float t[64][65];
    int j0 = (x >> 5) * 64, i0 = (x & 31) * 64;
    const float* src = adj + (size_t)b * NN * NN;
    for (int p = 0; p < 16; ++p) {
      int idx = p * 256 + tid;
      int i = idx >> 6, j = idx & 63;
      t[j][i] = src[(size_t)(i0 + i) * NN + (j0 + j)];
    }
    __syncthreads();
    unsigned short* dst = adjT + (size_t)b * NN * NN;
    for (int p = 0; p < 4; ++p) {
      int idx = p * 256 + tid;
      int j = idx >> 4, i4 = (idx & 15) * 4;
      ushort4 r;
      r.x = f2b(t[j][i4 + 0]); r.y = f2b(t[j][i4 + 1]);
      r.z = f2b(t[j][i4 + 2]); r.w = f2b(t[j][i4 + 3]);
      *(ushort4*)(dst + (size_t)(j0 + j) * NN + (i0 + i4)) = r;
    }
  } else {
    int i0 = (x - 1024) * 64;
    int lane = tid & 63, w = tid >> 6;
    int q = lane >> 4, m = lane & 15;
    f32x4 acc[8];
#pragma unroll
    for (int t = 0; t < 8; ++t)
#pragma unroll
      for (int r = 0; r < 4; ++r) acc[t][r] = 0.f;
    int irow = i0 + w * 16 + m;
    const float* hrow = X + ((size_t)b * NN + irow) * DD;
#pragma unroll
    for (int kk = 0; kk < 4; ++kk) {
      int d0 = kk * 32 + q * 8;
      float4 h0 = *(const float4*)(hrow + d0);
      float4 h1 = *(const float4*)(hrow + d0 + 4);
      union { bf16x8 v; unsigned short s[8]; } ub;
      ub.s[0] = f2b(h0.x); ub.s[1] = f2b(h0.y); ub.s[2] = f2b(h0.z); ub.s[3] = f2b(h0.w);
      ub.s[4] = f2b(h1.x); ub.s[5] = f2b(h1.y); ub.s[6] = f2b(h1.z); ub.s[7] = f2b(h1.w);
#pragma unroll
      for (int mt = 0; mt < 8; ++mt) {
        bf16x8 af = *(const bf16x8*)(WT + (mt * 16 + m) * 128 + d0);
        acc[mt] = __builtin_amdgcn_mfma_f32_16x16x32_bf16(af, ub.v, acc[mt], 0, 0, 0);
      }
    }
    unsigned short* dst = hwT + (size_t)b * DD * NN;
#pragma unroll
    for (int mt = 0; mt < 8; ++mt)
#pragma unroll
      for (int r = 0; r < 4; ++r)
        dst[(size_t)(mt * 16 + q * 4 + r) * NN + irow] = f2b(acc[mt][r]);
  }
}

// pacc[ks][b][j][e] (bf16) = sum_{i in ks-chunk} adjT[j][i]*hwT[e][i]
__global__ __launch_bounds__(256, 4) void k_gemm2(const unsigned short* __restrict__ adjT,
                                                  const unsigned short* __restrict__ hwT,
                                                  unsigned short* __restrict__ pacc) {
  __shared__ __align__(16) unsigned short sAB[16384];
  unsigned short* sA = sAB;
  unsigned short* sH = sAB + 8192;
  int tid = threadIdx.x;
  int lane = tid & 63, w = tid >> 6;
  int q = lane >> 4, m = lane & 15;
  int wj = w & 1, we = w >> 1;
  int b = blockIdx.y, j0 = blockIdx.x * 128, ks = blockIdx.z;
  const unsigned short* At = adjT + (size_t)b * NN * NN;
  const unsigned short* Ht = hwT + (size_t)b * DD * NN;

  const unsigned short* aSrc[4];
  const unsigned short* hSrc[4];
#pragma unroll
  for (int it = 0; it < 4; ++it) {
    int p = (w * 4 + it) * 64 + lane;
    int r = p >> 3, cg = (p & 7) ^ (r & 7);
    aSrc[it] = At + (size_t)(j0 + r) * NN + ks * KC + cg * 8;
    hSrc[it] = Ht + (size_t)r * NN + ks * KC + cg * 8;
  }

  f32x4 acc[4][4];
#pragma unroll
  for (int i = 0; i < 4; ++i)
#pragma unroll
    for (int j = 0; j < 4; ++j)
#pragma unroll
      for (int r = 0; r < 4; ++r) acc[i][j][r] = 0.f;

  for (int k0 = 0; k0 < KC; k0 += 64) {
    __syncthreads();
#pragma unroll
    for (int it = 0; it < 4; ++it) {
      __builtin_amdgcn_global_load_lds((glob_u32*)aSrc[it],
                                       (lds_u32*)(sA + (w * 4 + it) * 512), 16, 0, 0);
      __builtin_amdgcn_global_load_lds((glob_u32*)hSrc[it],
                                       (lds_u32*)(sH + (w * 4 + it) * 512), 16, 0, 0);
      aSrc[it] += 64; hSrc[it] += 64;
    }
    __syncthreads();
#pragma unroll
    for (int kk = 0; kk < 2; ++kk) {
      bf16x8 af[4], bf[4];
#pragma unroll
      for (int mt = 0; mt < 4; ++mt) {
        int r = wj * 64 + mt * 16 + m;
        int c = (kk * 4 + q) ^ (r & 7);
        af[mt] = *(const bf16x8*)(sA + r * 64 + c * 8);
      }
#pragma unroll
      for (int nt = 0; nt < 4; ++nt) {
        int r = we * 64 + nt * 16 + m;
        int c = (kk * 4 + q) ^ (r & 7);
        bf[nt] = *(const bf16x8*)(sH + r * 64 + c * 8);
      }
#pragma unroll
      for (int mt = 0; mt < 4; ++mt)
#pragma unroll
        for (int nt = 0; nt < 4; ++nt)
          acc[mt][nt] = __builtin_amdgcn_mfma_f32_16x16x32_bf16(af[mt], bf[nt], acc[mt][nt], 0, 0, 0);
    }
  }
  __syncthreads();
#pragma unroll
  for (int mt = 0; mt < 4; ++mt)
#pragma unroll
    for (int nt = 0; nt < 4; ++nt)
#pragma unroll
      for (int r = 0; r < 4; ++r) {
        int row = wj * 64 + mt * 16 + q * 4 + r;
        int col = we * 64 + nt * 16 + m;
        sAB[row * 128 + col] = f2b(acc[mt][nt][r]);
      }
  __syncthreads();
  unsigned short* P = pacc + ((size_t)ks * BB + b) * (size_t)NN * DD + (size_t)j0 * DD;
#pragma unroll
  for (int p = 0; p < 8; ++p) {
    int idx = p * 256 + tid;
    int row = idx >> 4, c8 = (idx & 15) * 8;
    *(u32x4*)(P + (size_t)row * DD + c8) = *(const u32x4*)(sAB + row * 128 + c8);
  }
}

// Fused: z = sum_ks pacc + bias + res; LN+ReLU -> out fp32; (doW) gemm1 -> hwT.
// 32 rows / 128 threads / 17 KB LDS; W^T frags read from global (L2).
__global__ __launch_bounds__(128) void k_rg1(const unsigned short* __restrict__ pacc,
                                             const float* __restrict__ res,
                                             const float* __restrict__ bias,
                                             const float* __restrict__ gamma,
                                             const float* __restrict__ beta,
                                             const unsigned short* __restrict__ WTn,
                                             float* __restrict__ outf,
                                             unsigned short* __restrict__ hwT,
                                             int doW) {
  __shared__ float z[32 * 132];
  __shared__ float smu[32], srs[32];
  int tid = threadIdx.x;
  int b = blockIdx.y, j0 = blockIdx.x * 32;
  size_t base = ((size_t)b * NN + j0) * DD;
  const size_t kstride = (size_t)BB * NN * DD;
  const unsigned short* P = pacc + base;
#pragma unroll
  for (int p = 0; p < 4; ++p) {
    int idx = p * 128 + tid;
    int j = idx >> 4, c8 = (idx & 15) * 8;
    size_t off = (size_t)j * DD + c8;
    float v[8];
    const float4* r4 = (const float4*)(res + base + off);
    float4 r0 = r4[0], r1 = r4[1];
    const float4* bi4 = (const float4*)(bias + c8);
    float4 b0 = bi4[0], b1 = bi4[1];
    v[0] = r0.x + b0.x; v[1] = r0.y + b0.y; v[2] = r0.z + b0.z; v[3] = r0.w + b0.w;
    v[4] = r1.x + b1.x; v[5] = r1.y + b1.y; v[6] = r1.z + b1.z; v[7] = r1.w + b1.w;
#pragma unroll
    for (int s = 0; s < KS; ++s) {
      union { u32x4 u; unsigned short h[8]; } up;
      up.u = *(const u32x4*)(P + s * kstride + off);
#pragma unroll
      for (int t = 0; t < 8; ++t) v[t] += b2f(up.h[t]);
    }
#pragma unroll
    for (int t = 0; t < 8; ++t) z[j * 132 + c8 + t] = v[t];
  }
  __syncthreads();
  {
    int j = tid >> 2, s = tid & 3;
    float sum = 0.f, sq = 0.f;
#pragma unroll
    for (int k = 0; k < 32; ++k) {
      float v = z[j * 132 + s + 4 * k];  // interleaved: bank-conflict-free
      sum += v; sq += v * v;
    }
    sum += __shfl_xor(sum, 1); sq += __shfl_xor(sq, 1);
    sum += __shfl_xor(sum, 2); sq += __shfl_xor(sq, 2);
    if (s == 0) {
      float mu = sum * (1.f / 128.f);
      float var = sq * (1.f / 128.f) - mu * mu;
      smu[j] = mu;
      srs[j] = rsqrtf(var + 1e-5f);
    }
  }
  __syncthreads();
  {
    float g = gamma[tid], bt = beta[tid];
#pragma unroll
    for (int p = 0; p < 32; ++p) {
      float v = (z[p * 132 + tid] - smu[p]) * srs[p] * g + bt;
      v = fmaxf(v, 0.f);
      outf[base + p * 128 + tid] = v;
      z[p * 132 + tid] = v;
    }
  }
  if (!doW) return;
  __syncthreads();
  int lane = tid & 63, w = tid >> 6;
  int q = lane >> 4, m = lane & 15;
  f32x4 acc[8];
#pragma unroll
  for (int t = 0; t < 8; ++t)
#pragma unroll
    for (int r = 0; r < 4; ++r) acc[t][r] = 0.f;
  int irow = j0 + w * 16 + m;
  const float* hrow = &z[(w * 16 + m) * 132];
#pragma unroll
  for (int kk = 0; kk < 4; ++kk) {
    int d0 = kk * 32 + q * 8;
    float4 h0 = *(const float4*)(hrow + d0);
    float4 h1 = *(const float4*)(hrow + d0 + 4);
    union { bf16x8 v; unsigned short s[8]; } ub;
    ub.s[0] = f2b(h0.x); ub.s[1] = f2b(h0.y); ub.s[2] = f2b(h0.z); ub.s[3] = f2b(h0.w);
    ub.s[4] = f2b(h1.x); ub.s[5] = f2b(h1.y); ub.s[6] = f2b(h1.z); ub.s[7] = f2b(h1.w);
#pragma unroll
    for (int mt = 0; mt < 8; ++mt) {
      bf16x8 af = *(const bf16x8*)(WTn + (mt * 16 + m) * 128 + d0);
      acc[mt] = __builtin_amdgcn_mfma_f32_16x16x32_bf16(af, ub.v, acc[mt], 0, 0, 0);
    }
  }
  unsigned short* dst = hwT + (size_t)b * DD * NN;
#pragma unroll
  for (int mt = 0; mt < 8; ++mt)
#pragma unroll
    for (int r = 0; r < 4; ++r)
      dst[(size_t)(mt * 16 + q * 4 + r) * NN + irow] = f2b(acc[mt][r]);
}

extern "C" void kernel_launch(void* const* d_in, const int* in_sizes, int n_in,
                              void* d_out, int out_size, void* d_ws, size_t ws_size,
                              hipStream_t stream) {
  const float* X   = (const float*)d_in[0];
  const float* adj = (const float*)d_in[1];
  const float* Ws  = (const float*)d_in[2];
  const float* bs  = (const float*)d_in[3];
  const float* gms = (const float*)d_in[4];
  const float* bts = (const float*)d_in[5];
  float* out = (float*)d_out;

  // ws: adjT bf16 (134MB) | hwT bf16 (8.4MB) | pacc bf16 (33.6MB) | WT bf16 (96KB)
  unsigned short* adjT = (unsigned short*)d_ws;
  unsigned short* hwT  = adjT + (size_t)BB * NN * NN;
  unsigned short* pacc = hwT + (size_t)BB * DD * NN;
  unsigned short* WT   = pacc + (size_t)KS * BB * NN * DD;

  k_wt<<<dim3(2, 2, 3), 256, 0, stream>>>(Ws, WT);
  k_pre<<<dim3(1056, BB), 256, 0, stream>>>(adj, adjT, X, WT, hwT);
  for (int l = 0; l < 3; ++l) {
    k_gemm2<<<dim3(NN / 128, BB, KS), 256, 0, stream>>>(adjT, hwT, pacc);
    const float* res = (l == 0) ? X : (const float*)out;
    const unsigned short* WTn = WT + (size_t)((l < 2) ? (l + 1) : 0) * DD * DD;
    k_rg1<<<dim3(NN / 32, BB), 128, 0, stream>>>(pacc, res, bs + l * DD,
                                                 gms + l * DD, bts + l * DD,
                                                 WTn, out, hwT, (l < 2) ? 1 : 0);
  }
}

// Round 5
// 552.866 us; speedup vs baseline: 1.2822x; 1.2822x over previous
//
#include <hip/hip_runtime.h>

#define BB 16
#define NN 2048
#define DD 128
#define KS 4
#define KC (NN / KS)

typedef __attribute__((ext_vector_type(8))) __bf16 bf16x8;
typedef __attribute__((ext_vector_type(4))) float f32x4;
typedef __attribute__((ext_vector_type(4))) unsigned int u32x4;
typedef __attribute__((address_space(3))) unsigned int lds_u32;
typedef __attribute__((address_space(1))) const unsigned int glob_u32;

static __device__ __forceinline__ unsigned short f2b(float f) {
  union { float f; unsigned int u; } c; c.f = f;
  unsigned int u = c.u;
  unsigned int r = (u + 0x7FFFu + ((u >> 16) & 1u)) >> 16;
  return (unsigned short)r;
}
static __device__ __forceinline__ float b2f(unsigned short u) {
  union { unsigned int u; float f; } c; c.u = ((unsigned int)u) << 16;
  return c.f;
}

// WT[l][e][d] = bf16(W[l][d][e])  -- 96 KB total, L2-resident afterwards
__global__ void k_wt(const float* __restrict__ W, unsigned short* __restrict__ WT) {
  __shared__ float t[64][65];
  int l = blockIdx.z, d0 = blockIdx.x * 64, e0 = blockIdx.y * 64;
  int tid = threadIdx.x;
  const float* src = W + (size_t)l * DD * DD;
  for (int p = 0; p < 16; ++p) {
    int idx = p * 256 + tid;
    int d = idx >> 6, e = idx & 63;
    t[e][d] = src[(size_t)(d0 + d) * DD + (e0 + e)];
  }
  __syncthreads();
  unsigned short* dst = WT + (size_t)l * DD * DD;
  for (int p = 0; p < 4; ++p) {
    int idx = p * 256 + tid;
    int e = idx >> 4, d4 = (idx & 15) * 4;
    ushort4 r;
    r.x = f2b(t[e][d4 + 0]); r.y = f2b(t[e][d4 + 1]);
    r.z = f2b(t[e][d4 + 2]); r.w = f2b(t[e][d4 + 3]);
    *(ushort4*)(dst + (size_t)(e0 + e) * DD + (d0 + d4)) = r;
  }
}

// Merged: x<1024 -> adj transpose tile; x>=1024 -> layer-0 gemm1 (X fp32, WT global frags)
__global__ __launch_bounds__(256) void k_pre(const float* __restrict__ adj,
                                             unsigned short* __restrict__ adjT,
                                             const float* __restrict__ X,
                                             const unsigned short* __restrict__ WT,
                                             unsigned short* __restrict__ hwT) {
  int b = blockIdx.y, x = blockIdx.x, tid = threadIdx.x;
  if (x < 1024) {
    __shared__ float t[64][65];
    int j0 = (x >> 5) * 64, i0 = (x & 31) * 64;
    const float* src = adj + (size_t)b * NN * NN;
    for (int p = 0; p < 16; ++p) {
      int idx = p * 256 + tid;
      int i = idx >> 6, j = idx & 63;
      t[j][i] = src[(size_t)(i0 + i) * NN + (j0 + j)];
    }
    __syncthreads();
    unsigned short* dst = adjT + (size_t)b * NN * NN;
    for (int p = 0; p < 4; ++p) {
      int idx = p * 256 + tid;
      int j = idx >> 4, i4 = (idx & 15) * 4;
      ushort4 r;
      r.x = f2b(t[j][i4 + 0]); r.y = f2b(t[j][i4 + 1]);
      r.z = f2b(t[j][i4 + 2]); r.w = f2b(t[j][i4 + 3]);
      *(ushort4*)(dst + (size_t)(j0 + j) * NN + (i0 + i4)) = r;
    }
  } else {
    int i0 = (x - 1024) * 64;
    int lane = tid & 63, w = tid >> 6;
    int q = lane >> 4, m = lane & 15;
    f32x4 acc[8];
#pragma unroll
    for (int t = 0; t < 8; ++t)
#pragma unroll
      for (int r = 0; r < 4; ++r) acc[t][r] = 0.f;
    int irow = i0 + w * 16 + m;
    const float* hrow = X + ((size_t)b * NN + irow) * DD;
#pragma unroll
    for (int kk = 0; kk < 4; ++kk) {
      int d0 = kk * 32 + q * 8;
      float4 h0 = *(const float4*)(hrow + d0);
      float4 h1 = *(const float4*)(hrow + d0 + 4);
      union { bf16x8 v; unsigned short s[8]; } ub;
      ub.s[0] = f2b(h0.x); ub.s[1] = f2b(h0.y); ub.s[2] = f2b(h0.z); ub.s[3] = f2b(h0.w);
      ub.s[4] = f2b(h1.x); ub.s[5] = f2b(h1.y); ub.s[6] = f2b(h1.z); ub.s[7] = f2b(h1.w);
#pragma unroll
      for (int mt = 0; mt < 8; ++mt) {
        bf16x8 af = *(const bf16x8*)(WT + (mt * 16 + m) * 128 + d0);
        acc[mt] = __builtin_amdgcn_mfma_f32_16x16x32_bf16(af, ub.v, acc[mt], 0, 0, 0);
      }
    }
    unsigned short* dst = hwT + (size_t)b * DD * NN;
#pragma unroll
    for (int mt = 0; mt < 8; ++mt)
#pragma unroll
      for (int r = 0; r < 4; ++r)
        dst[(size_t)(mt * 16 + q * 4 + r) * NN + irow] = f2b(acc[mt][r]);
  }
}

// pacc[ks][b][j][e] (bf16) = sum_{i in ks-chunk} adjT[j][i]*hwT[e][i]
// NOTE: plain launch_bounds(256). (256,4) caps VGPR at 128 -> acc spills in K-loop
// (R4 regression +149us). Kernel's natural allocation is ~160 VGPR, 3 blocks/CU.
__global__ __launch_bounds__(256) void k_gemm2(const unsigned short* __restrict__ adjT,
                                               const unsigned short* __restrict__ hwT,
                                               unsigned short* __restrict__ pacc) {
  __shared__ __align__(16) unsigned short sAB[16384];
  unsigned short* sA = sAB;
  unsigned short* sH = sAB + 8192;
  int tid = threadIdx.x;
  int lane = tid & 63, w = tid >> 6;
  int q = lane >> 4, m = lane & 15;
  int wj = w & 1, we = w >> 1;
  int b = blockIdx.y, j0 = blockIdx.x * 128, ks = blockIdx.z;
  const unsigned short* At = adjT + (size_t)b * NN * NN;
  const unsigned short* Ht = hwT + (size_t)b * DD * NN;

  const unsigned short* aSrc[4];
  const unsigned short* hSrc[4];
#pragma unroll
  for (int it = 0; it < 4; ++it) {
    int p = (w * 4 + it) * 64 + lane;
    int r = p >> 3, cg = (p & 7) ^ (r & 7);
    aSrc[it] = At + (size_t)(j0 + r) * NN + ks * KC + cg * 8;
    hSrc[it] = Ht + (size_t)r * NN + ks * KC + cg * 8;
  }

  f32x4 acc[4][4];
#pragma unroll
  for (int i = 0; i < 4; ++i)
#pragma unroll
    for (int j = 0; j < 4; ++j)
#pragma unroll
      for (int r = 0; r < 4; ++r) acc[i][j][r] = 0.f;

  for (int k0 = 0; k0 < KC; k0 += 64) {
    __syncthreads();
#pragma unroll
    for (int it = 0; it < 4; ++it) {
      __builtin_amdgcn_global_load_lds((glob_u32*)aSrc[it],
                                       (lds_u32*)(sA + (w * 4 + it) * 512), 16, 0, 0);
      __builtin_amdgcn_global_load_lds((glob_u32*)hSrc[it],
                                       (lds_u32*)(sH + (w * 4 + it) * 512), 16, 0, 0);
      aSrc[it] += 64; hSrc[it] += 64;
    }
    __syncthreads();
#pragma unroll
    for (int kk = 0; kk < 2; ++kk) {
      bf16x8 af[4], bf[4];
#pragma unroll
      for (int mt = 0; mt < 4; ++mt) {
        int r = wj * 64 + mt * 16 + m;
        int c = (kk * 4 + q) ^ (r & 7);
        af[mt] = *(const bf16x8*)(sA + r * 64 + c * 8);
      }
#pragma unroll
      for (int nt = 0; nt < 4; ++nt) {
        int r = we * 64 + nt * 16 + m;
        int c = (kk * 4 + q) ^ (r & 7);
        bf[nt] = *(const bf16x8*)(sH + r * 64 + c * 8);
      }
#pragma unroll
      for (int mt = 0; mt < 4; ++mt)
#pragma unroll
        for (int nt = 0; nt < 4; ++nt)
          acc[mt][nt] = __builtin_amdgcn_mfma_f32_16x16x32_bf16(af[mt], bf[nt], acc[mt][nt], 0, 0, 0);
    }
  }
  __syncthreads();
#pragma unroll
  for (int mt = 0; mt < 4; ++mt)
#pragma unroll
    for (int nt = 0; nt < 4; ++nt)
#pragma unroll
      for (int r = 0; r < 4; ++r) {
        int row = wj * 64 + mt * 16 + q * 4 + r;
        int col = we * 64 + nt * 16 + m;
        sAB[row * 128 + col] = f2b(acc[mt][nt][r]);
      }
  __syncthreads();
  unsigned short* P = pacc + ((size_t)ks * BB + b) * (size_t)NN * DD + (size_t)j0 * DD;
#pragma unroll
  for (int p = 0; p < 8; ++p) {
    int idx = p * 256 + tid;
    int row = idx >> 4, c8 = (idx & 15) * 8;
    *(u32x4*)(P + (size_t)row * DD + c8) = *(const u32x4*)(sAB + row * 128 + c8);
  }
}

// Fused: z = sum_ks pacc + bias + res; LN+ReLU -> out fp32; (doW) gemm1 -> hwT.
// 64 rows / 256 threads; sW staged from pre-transposed WT (coalesced, conflict-free).
__global__ __launch_bounds__(256) void k_rg1(const unsigned short* __restrict__ pacc,
                                             const float* __restrict__ res,
                                             const float* __restrict__ bias,
                                             const float* __restrict__ gamma,
                                             const float* __restrict__ beta,
                                             const unsigned short* __restrict__ WTn,
                                             float* __restrict__ outf,
                                             unsigned short* __restrict__ hwT,
                                             int doW) {
  __shared__ float z[64 * 132];
  __shared__ float smu[64], srs[64];
  __shared__ unsigned short sW[128 * 132];
  int tid = threadIdx.x;
  int lane = tid & 63, w = tid >> 6;
  int q = lane >> 4, m = lane & 15;
  int b = blockIdx.y, j0 = blockIdx.x * 64;
  if (doW) {
#pragma unroll
    for (int p = 0; p < 8; ++p) {  // 128x128 ushorts as 16B chunks from WT[e][d]
      int idx = p * 256 + tid;
      int e = idx >> 4, d8 = (idx & 15) * 8;
      *(u32x4*)(sW + e * 132 + d8) = *(const u32x4*)(WTn + e * 128 + d8);
    }
  }
  size_t base = ((size_t)b * NN + j0) * DD;
  const size_t kstride = (size_t)BB * NN * DD;
  const unsigned short* P = pacc + base;
#pragma unroll
  for (int p = 0; p < 4; ++p) {
    int idx = p * 256 + tid;       // 16B-chunk index in 64x128
    int j = idx >> 4, c8 = (idx & 15) * 8;
    size_t off = (size_t)j * DD + c8;
    float v[8];
    const float4* r4 = (const float4*)(res + base + off);
    float4 r0 = r4[0], r1 = r4[1];
    const float4* bi4 = (const float4*)(bias + c8);
    float4 b0 = bi4[0], b1 = bi4[1];
    v[0] = r0.x + b0.x; v[1] = r0.y + b0.y; v[2] = r0.z + b0.z; v[3] = r0.w + b0.w;
    v[4] = r1.x + b1.x; v[5] = r1.y + b1.y; v[6] = r1.z + b1.z; v[7] = r1.w + b1.w;
#pragma unroll
    for (int s = 0; s < KS; ++s) {
      union { u32x4 u; unsigned short h[8]; } up;
      up.u = *(const u32x4*)(P + s * kstride + off);
#pragma unroll
      for (int t = 0; t < 8; ++t) v[t] += b2f(up.h[t]);
    }
#pragma unroll
    for (int t = 0; t < 8; ++t) z[j * 132 + c8 + t] = v[t];
  }
  __syncthreads();
  {
    int j = tid >> 2, s = tid & 3;
    float sum = 0.f, sq = 0.f;
#pragma unroll
    for (int k = 0; k < 32; ++k) {
      float v = z[j * 132 + s + 4 * k];  // interleaved: 2-way max
      sum += v; sq += v * v;
    }
    sum += __shfl_xor(sum, 1); sq += __shfl_xor(sq, 1);
    sum += __shfl_xor(sum, 2); sq += __shfl_xor(sq, 2);
    if (s == 0) {
      float mu = sum * (1.f / 128.f);
      float var = sq * (1.f / 128.f) - mu * mu;
      smu[j] = mu;
      srs[j] = rsqrtf(var + 1e-5f);
    }
  }
  __syncthreads();
  {
    int e = tid & 127;
    float g = gamma[e], bt = beta[e];
#pragma unroll
    for (int p = 0; p < 32; ++p) {
      int idx = p * 256 + tid;
      int j = idx >> 7;
      float v = (z[j * 132 + e] - smu[j]) * srs[j] * g + bt;
      v = fmaxf(v, 0.f);
      outf[base + idx] = v;
      z[j * 132 + e] = v;   // h for phase-2 gemm1 (same thread, same slot: no race)
    }
  }
  if (!doW) return;
  __syncthreads();
  f32x4 acc[8];
#pragma unroll
  for (int t = 0; t < 8; ++t)
#pragma unroll
    for (int r = 0; r < 4; ++r) acc[t][r] = 0.f;
  int irow = j0 + w * 16 + m;
  const float* hrow = &z[(w * 16 + m) * 132];
#pragma unroll
  for (int kk = 0; kk < 4; ++kk) {
    int d0 = kk * 32 + q * 8;
    float4 h0 = *(const float4*)(hrow + d0);
    float4 h1 = *(const float4*)(hrow + d0 + 4);
    union { bf16x8 v; unsigned short s[8]; } ub;
    ub.s[0] = f2b(h0.x); ub.s[1] = f2b(h0.y); ub.s[2] = f2b(h0.z); ub.s[3] = f2b(h0.w);
    ub.s[4] = f2b(h1.x); ub.s[5] = f2b(h1.y); ub.s[6] = f2b(h1.z); ub.s[7] = f2b(h1.w);
#pragma unroll
    for (int mt = 0; mt < 8; ++mt) {
      bf16x8 af = *(const bf16x8*)(sW + (mt * 16 + m) * 132 + d0);
      acc[mt] = __builtin_amdgcn_mfma_f32_16x16x32_bf16(af, ub.v, acc[mt], 0, 0, 0);
    }
  }
  unsigned short* dst = hwT + (size_t)b * DD * NN;
#pragma unroll
  for (int mt = 0; mt < 8; ++mt)
#pragma unroll
    for (int r = 0; r < 4; ++r)
      dst[(size_t)(mt * 16 + q * 4 + r) * NN + irow] = f2b(acc[mt][r]);
}

extern "C" void kernel_launch(void* const* d_in, const int* in_sizes, int n_in,
                              void* d_out, int out_size, void* d_ws, size_t ws_size,
                              hipStream_t stream) {
  const float* X   = (const float*)d_in[0];
  const float* adj = (const float*)d_in[1];
  const float* Ws  = (const float*)d_in[2];
  const float* bs  = (const float*)d_in[3];
  const float* gms = (const float*)d_in[4];
  const float* bts = (const float*)d_in[5];
  float* out = (float*)d_out;

  // ws: adjT bf16 (134MB) | hwT bf16 (8.4MB) | pacc bf16 (33.6MB) | WT bf16 (96KB)
  unsigned short* adjT = (unsigned short*)d_ws;
  unsigned short* hwT  = adjT + (size_t)BB * NN * NN;
  unsigned short* pacc = hwT + (size_t)BB * DD * NN;
  unsigned short* WT   = pacc + (size_t)KS * BB * NN * DD;

  k_wt<<<dim3(2, 2, 3), 256, 0, stream>>>(Ws, WT);
  k_pre<<<dim3(1056, BB), 256, 0, stream>>>(adj, adjT, X, WT, hwT);
  for (int l = 0; l < 3; ++l) {
    k_gemm2<<<dim3(NN / 128, BB, KS), 256, 0, stream>>>(adjT, hwT, pacc);
    const float* res = (l == 0) ? X : (const float*)out;
    const unsigned short* WTn = WT + (size_t)((l < 2) ? (l + 1) : 0) * DD * DD;
    k_rg1<<<dim3(NN / 64, BB), 256, 0, stream>>>(pacc, res, bs + l * DD,
                                                 gms + l * DD, bts + l * DD,
                                                 WTn, out, hwT, (l < 2) ? 1 : 0);
  }
}